// Round 15
// baseline (241.590 us; speedup 1.0000x reference)
//
#include <hip/hip_runtime.h>

typedef _Float16 f16;
typedef __attribute__((ext_vector_type(8))) _Float16 h8;
typedef __attribute__((ext_vector_type(4))) _Float16 h4;
typedef __attribute__((ext_vector_type(4))) float f4;
typedef __attribute__((ext_vector_type(16))) float f16x;
typedef __attribute__((ext_vector_type(4))) unsigned u4;

#define MFMA(a, b, c) __builtin_amdgcn_mfma_f32_16x16x32_f16(a, b, c, 0, 0, 0)
#define MFMA32(a, b, c) __builtin_amdgcn_mfma_f32_32x32x16_f16(a, b, c, 0, 0, 0)

// Q prescale: 1/sqrt(64) * log2(e), folded into qkv epilogue -> softmax in base-2
#define QSCALE 0.18033688011112042f

__device__ __forceinline__ void gload16(const void* g, void* l) {
    __builtin_amdgcn_global_load_lds((const __attribute__((address_space(1))) void*)g,
                                     (__attribute__((address_space(3))) void*)l, 16, 0, 0);
}

__device__ __forceinline__ float fexp2(float x) {
    float r;
    asm("v_exp_f32 %0, %1" : "=v"(r) : "v"(x));
    return r;
}

// pack 2 f32 -> 2 f16 (RTZ) in one u32
__device__ __forceinline__ unsigned pkh(float a, float b) {
    auto r = __builtin_amdgcn_cvt_pkrtz(a, b);  // __fp16 ext_vector(2)
    return __builtin_bit_cast(unsigned, r);
}

// v_permlane32_swap_b32: a[l>=32] <-> b[l<32]  (both operands modified)
__device__ __forceinline__ void plswap(unsigned& a, unsigned& b) {
    asm volatile("v_permlane32_swap_b32 %0, %1" : "+v"(a), "+v"(b));
}

// ---------------- conversion kernels ----------------

__global__ __launch_bounds__(256) void cvt_f16_kernel(const float* __restrict__ in,
                                                      f16* __restrict__ out, int n8) {
    int i = blockIdx.x * blockDim.x + threadIdx.x;
    if (i >= n8) return;
    const float4* p = (const float4*)in + (size_t)i * 2;
    float4 a = p[0], b = p[1];
    h8 o;
    o[0] = (f16)a.x; o[1] = (f16)a.y; o[2] = (f16)a.z; o[3] = (f16)a.w;
    o[4] = (f16)b.x; o[5] = (f16)b.y; o[6] = (f16)b.z; o[7] = (f16)b.w;
    *((h8*)out + i) = o;
}

// in: [R][Cc] f32 row-major -> out: [Cc][R] f16 row-major
__global__ __launch_bounds__(256) void transpose_cvt(const float* __restrict__ in,
                                                     f16* __restrict__ out, int R, int Cc) {
    __shared__ float tile[32][33];
    int tx = threadIdx.x, ty = threadIdx.y;
    int c0 = blockIdx.x * 32, r0 = blockIdx.y * 32;
#pragma unroll
    for (int k = 0; k < 32; k += 8)
        tile[ty + k][tx] = in[(size_t)(r0 + ty + k) * Cc + c0 + tx];
    __syncthreads();
#pragma unroll
    for (int k = 0; k < 32; k += 8)
        out[(size_t)(c0 + ty + k) * R + r0 + tx] = (f16)tile[tx][ty + k];
}

// ---------------- GEMM core (128x128 tile, BK=64, 4 waves, swizzled LDS) ----------------

__device__ __forceinline__ void gemm_core(const f16* __restrict__ A, const f16* __restrict__ Bt,
                                          int K, int m0, int n0,
                                          f16* lA, f16* lB, f4 acc[4][4]) {
    const int tid = threadIdx.x, lane = tid & 63, wave = tid >> 6;
    const int wm = (wave >> 1) * 64, wn = (wave & 1) * 64;
    for (int k0 = 0; k0 < K; k0 += 64) {
        __syncthreads();
#pragma unroll
        for (int i = 0; i < 4; i++) {
            int s = i * 256 + wave * 64 + lane;
            int row = s >> 3;
            int gc = ((s & 7) ^ (row & 7)) * 8;
            gload16(A + (size_t)(m0 + row) * K + k0 + gc, lA + (i * 256 + wave * 64) * 8);
        }
#pragma unroll
        for (int i = 0; i < 4; i++) {
            int s = i * 256 + wave * 64 + lane;
            int row = s >> 3;
            int gc = ((s & 7) ^ (row & 7)) * 8;
            gload16(Bt + (size_t)(n0 + row) * K + k0 + gc, lB + (i * 256 + wave * 64) * 8);
        }
        __syncthreads();
#pragma unroll
        for (int kk = 0; kk < 2; kk++) {
            h8 af[4], bg[4];
#pragma unroll
            for (int im = 0; im < 4; im++) {
                int row = wm + im * 16 + (lane & 15);
                int pc = (kk * 4 + (lane >> 4)) ^ (row & 7);
                af[im] = *(const h8*)(lA + row * 64 + pc * 8);
            }
#pragma unroll
            for (int in = 0; in < 4; in++) {
                int row = wn + in * 16 + (lane & 15);
                int pc = (kk * 4 + (lane >> 4)) ^ (row & 7);
                bg[in] = *(const h8*)(lB + row * 64 + pc * 8);
            }
#pragma unroll
            for (int im = 0; im < 4; im++)
#pragma unroll
                for (int in = 0; in < 4; in++)
                    acc[im][in] = MFMA(af[im], bg[in], acc[im][in]);
        }
    }
}

// ---------------- QKV GEMM: writes Q (prescaled), K [BH][T][64], V^T [BH][64][T] ----------------

__global__ __launch_bounds__(256) void qkv_gemm(const f16* __restrict__ A, const f16* __restrict__ Bt,
                                                const float* __restrict__ bias,
                                                f16* __restrict__ Qo, f16* __restrict__ Ko,
                                                f16* __restrict__ Vo) {
    __shared__ f16 lA[128 * 64], lB[128 * 64];
    f4 acc[4][4];
    const f4 zz = {0.f, 0.f, 0.f, 0.f};
#pragma unroll
    for (int i = 0; i < 4; i++)
#pragma unroll
        for (int j = 0; j < 4; j++) acc[i][j] = zz;

    const int swz = (blockIdx.x & 7) * 192 + (blockIdx.x >> 3);  // XCD-chunked (1536 = 8*192)
    const int nb = swz % 24, mb = swz / 24;
    gemm_core(A, Bt, 1024, mb * 128, nb * 128, lA, lB, acc);

    const int lane = threadIdx.x & 63, wave = threadIdx.x >> 6;
    const int wm = (wave >> 1) * 64, wn = (wave & 1) * 64;
#pragma unroll
    for (int im = 0; im < 4; im++) {
        int m4 = mb * 128 + wm + im * 16 + (lane >> 4) * 4;
        int b = m4 >> 11, t0 = m4 & 2047;
#pragma unroll
        for (int in = 0; in < 4; in++) {
            int n = nb * 128 + wn + in * 16 + (lane & 15);
            float bb = bias[n];
            int sec = n >> 10, cc = n & 1023, hh = cc >> 6, d = cc & 63;
            if (sec == 2) {
                h4 pv;
#pragma unroll
                for (int r = 0; r < 4; r++) pv[r] = (f16)(acc[im][in][r] + bb);
                *(h4*)(Vo + ((size_t)(b * 16 + hh) * 64 + d) * 2048 + t0) = pv;
            } else {
                f16* dst = sec ? Ko : Qo;
                float sc = sec ? 1.0f : QSCALE;  // Q prescaled for base-2 softmax
                size_t base = ((size_t)(b * 16 + hh) * 2048 + t0) * 64 + d;
#pragma unroll
                for (int r = 0; r < 4; r++)
                    dst[base + (size_t)r * 64] = (f16)((acc[im][in][r] + bb) * sc);
            }
        }
    }
}

// ---------------- Proj GEMM: f32 output + bias ----------------

__global__ __launch_bounds__(256) void proj_gemm(const f16* __restrict__ A, const f16* __restrict__ Bt,
                                                 const float* __restrict__ bias,
                                                 float* __restrict__ out) {
    __shared__ f16 lA[128 * 64], lB[128 * 64];
    f4 acc[4][4];
    const f4 zz = {0.f, 0.f, 0.f, 0.f};
#pragma unroll
    for (int i = 0; i < 4; i++)
#pragma unroll
        for (int j = 0; j < 4; j++) acc[i][j] = zz;

    const int swz = (blockIdx.x & 7) * 64 + (blockIdx.x >> 3);  // XCD-chunked (512 = 8*64)
    const int nb = swz & 7, mb = swz >> 3;
    gemm_core(A, Bt, 1024, mb * 128, nb * 128, lA, lB, acc);

    const int lane = threadIdx.x & 63, wave = threadIdx.x >> 6;
    const int wm = (wave >> 1) * 64, wn = (wave & 1) * 64;
#pragma unroll
    for (int im = 0; im < 4; im++) {
        int m4 = mb * 128 + wm + im * 16 + (lane >> 4) * 4;
#pragma unroll
        for (int in = 0; in < 4; in++) {
            int n = nb * 128 + wn + in * 16 + (lane & 15);
            float bb = bias[n];
#pragma unroll
            for (int r = 0; r < 4; r++)
                out[(size_t)(m4 + r) * 1024 + n] = acc[im][in][r] + bb;
        }
    }
}

// ---------------- Flash attention: 1-wave blocks, complementary pairs, KVBLK=64 ----------------
// Q(prescaled),K: [BH][2048][64] f16; Vg: [BH][64][2048] f16 (transposed); O: [B][2048][1024] f16
// Grid 2048 x 64 threads: block p does q-tiles (63-p) then (p); ~33 K-tiles of 64 each,
// uniform compute by construction; 8 blocks/CU flat. Waves fully independent (no barriers).
// KVBLK=64 (R9 tile shape in 1-wave packaging): halves per-tile overhead, doubles in-wave
// ILP (s0/s1 QK chains, 32 batched exp2, 4 PV chains) - targets the latency-bound chain.
// vmcnt choreography (issue order V(it) then K(it+1)):
//   vmcnt(16) before QK  -> K(it) in LDS ready, 16 younger ops in flight
//   vmcnt(8)  before PV  -> V(it) regs ready, K(it+1)'s 8 still in flight
// Only the LAST tile needs causal masking (proven: non-last k0+63 < qw for both parities).
// Swapped QK^T (S^T = K.Q^T, mfma_32x32x16), in-register softmax (base-2, defer-max),
// P->A via cvt_pkrtz + permlane32_swap (HW-verified R9).

#define ASM_VMCNT(N) asm volatile("s_waitcnt vmcnt(" #N ")" ::: "memory")

__device__ __forceinline__ void attn_tile64(int k0, bool last, bool stage_next,
                                            int lane, int hi, int ln, int qw,
                                            const f16* __restrict__ Kb,
                                            const f16* __restrict__ Vb,
                                            const f16* lKcur, f16* lKnxt,
                                            const h8 (&qf)[4],
                                            float& mrun, float& lpart, f16x& y0, f16x& y1) {
    const f16* Vt = Vb + k0;
    // V(it) fragment loads (8) - issued FIRST (oldest of this tile's ops)
    h8 vf[4][2];
#pragma unroll
    for (int ks = 0; ks < 4; ks++)
#pragma unroll
        for (int j = 0; j < 2; j++)
            vf[ks][j] = *(const h8*)(Vt + (size_t)(j * 32 + ln) * 2048 + ks * 16 + hi * 8);

    if (stage_next) {
        // K(it+1) -> other LDS buffer (8 x gload16 = 8KB)
#pragma unroll
        for (int i = 0; i < 8; i++) {
            int s = i * 64 + lane;
            int row = s >> 3;
            int gc = ((s & 7) ^ (row & 7)) * 8;
            gload16(Kb + (size_t)(k0 + 64 + row) * 64 + gc, lKnxt + i * 512);
        }
        ASM_VMCNT(16);  // K(it) ready; this tile's 16 ops stay in flight
    } else {
        ASM_VMCNT(8);   // K(it) ready; V(it)'s 8 remain
    }
    __builtin_amdgcn_sched_barrier(0);

    // S^T = K.Q^T: s0 covers k in [k0,k0+32), s1 in [k0+32,k0+64); lane owns q = qw+ln
    f16x s0, s1;
#pragma unroll
    for (int r = 0; r < 16; r++) { s0[r] = 0.f; s1[r] = 0.f; }
    __builtin_amdgcn_s_setprio(1);
#pragma unroll
    for (int dd = 0; dd < 4; dd++) {
        const int c = (dd * 2 + hi) ^ (ln & 7);  // swizzled 16B-chunk index
        h8 ka = *(const h8*)(lKcur + ln * 64 + c * 8);
        h8 kb = *(const h8*)(lKcur + (32 + ln) * 64 + c * 8);
        s0 = MFMA32(ka, qf[dd], s0);
        s1 = MFMA32(kb, qf[dd], s1);
    }
    __builtin_amdgcn_s_setprio(0);

    if (last) {  // diagonal tile: mask k > q (q = qw+ln)
        const int qg = qw + ln;
#pragma unroll
        for (int r = 0; r < 16; r++) {
            int kl = (r & 3) + 8 * (r >> 2) + 4 * hi;
            if (k0 + kl > qg) s0[r] = -3e38f;
            if (k0 + 32 + kl > qg) s1[r] = -3e38f;
        }
    }

    // register-local softmax (base-2, defer-max); 32 independent exp2s
    float vmax = fmaxf(s0[0], s1[0]);
#pragma unroll
    for (int r = 1; r < 16; r++) vmax = fmaxf(vmax, fmaxf(s0[r], s1[r]));
    vmax = fmaxf(vmax, __shfl_xor(vmax, 32));
    if (!__all(vmax <= mrun + 8.0f)) {
        float mnew = fmaxf(mrun, vmax);
        float sc = fexp2(mrun - mnew);
        lpart *= sc;
        mrun = mnew;
#pragma unroll
        for (int r = 0; r < 16; r++) {
            float scy = __shfl(sc, (r & 3) + 8 * (r >> 2) + 4 * hi);
            y0[r] *= scy;
            y1[r] *= scy;
        }
    }
    float ls = 0.f;
#pragma unroll
    for (int r = 0; r < 16; r++) {
        float p0 = fexp2(s0[r] - mrun);
        float p1 = fexp2(s1[r] - mrun);
        s0[r] = p0; s1[r] = p1;
        ls += p0 + p1;
    }
    lpart += ls;

    // P -> PV A-fragments: 16 cvt_pk + 8 permlane32_swap (no LDS; verified R9)
    h8 pa[4];
    {
        unsigned a0 = pkh(s0[0], s0[1]), a1 = pkh(s0[2], s0[3]);
        unsigned b0 = pkh(s0[4], s0[5]), b1 = pkh(s0[6], s0[7]);
        plswap(a0, b0); plswap(a1, b1);
        u4 w0; w0[0] = a0; w0[1] = a1; w0[2] = b0; w0[3] = b1;
        pa[0] = __builtin_bit_cast(h8, w0);
        unsigned c0 = pkh(s0[8], s0[9]), c1 = pkh(s0[10], s0[11]);
        unsigned d0 = pkh(s0[12], s0[13]), d1 = pkh(s0[14], s0[15]);
        plswap(c0, d0); plswap(c1, d1);
        u4 w1; w1[0] = c0; w1[1] = c1; w1[2] = d0; w1[3] = d1;
        pa[1] = __builtin_bit_cast(h8, w1);
        unsigned e0 = pkh(s1[0], s1[1]), e1 = pkh(s1[2], s1[3]);
        unsigned f0 = pkh(s1[4], s1[5]), f1 = pkh(s1[6], s1[7]);
        plswap(e0, f0); plswap(e1, f1);
        u4 w2; w2[0] = e0; w2[1] = e1; w2[2] = f0; w2[3] = f1;
        pa[2] = __builtin_bit_cast(h8, w2);
        unsigned g0 = pkh(s1[8], s1[9]), g1 = pkh(s1[10], s1[11]);
        unsigned h0 = pkh(s1[12], s1[13]), h1 = pkh(s1[14], s1[15]);
        plswap(g0, h0); plswap(g1, h1);
        u4 w3; w3[0] = g0; w3[1] = g1; w3[2] = h0; w3[3] = h1;
        pa[3] = __builtin_bit_cast(h8, w3);
    }

    // wait V(it) ready (8 remaining younger if staged = K(it+1), which may stay in flight)
    if (stage_next) { ASM_VMCNT(8); } else { ASM_VMCNT(0); }
    __builtin_amdgcn_sched_barrier(0);

    // Y += P V : 4 independent chains
    __builtin_amdgcn_s_setprio(1);
#pragma unroll
    for (int ks = 0; ks < 4; ks++) {
        y0 = MFMA32(pa[ks], vf[ks][0], y0);
        y1 = MFMA32(pa[ks], vf[ks][1], y1);
    }
    __builtin_amdgcn_s_setprio(0);
}

__global__ __launch_bounds__(64) void attn_kernel(const f16* __restrict__ Q,
                                                  const f16* __restrict__ K,
                                                  const f16* __restrict__ Vg,
                                                  f16* __restrict__ O) {
    __shared__ f16 lK[2][4096];  // [buf][64 rows x 64]
    const int lane = threadIdx.x;
    const int hi = lane >> 5, ln = lane & 31;
    const int bh = blockIdx.x & 63;
    const int p = (int)(blockIdx.x >> 6);  // 0..31
    const f16* Qb = Q + (size_t)bh * 2048 * 64;
    const f16* Kb = K + (size_t)bh * 2048 * 64;
    const f16* Vb = Vg + (size_t)bh * 64 * 2048;
    const int b = bh >> 4, hh = bh & 15;

    for (int ph = 0; ph < 2; ph++) {
        const int qt = ph ? p : 63 - p;  // complementary pair: uniform compute per block
        const int qw = qt * 32;

        // hoist Q fragments (B-operand): Q[qw+ln][dd*16 + hi*8 .. +8]
        h8 qf[4];
#pragma unroll
        for (int dd = 0; dd < 4; dd++)
            qf[dd] = *(const h8*)(Qb + (size_t)(qw + ln) * 64 + dd * 16 + hi * 8);

        float mrun = -3e38f, lpart = 0.f;
        f16x y0, y1;
#pragma unroll
        for (int r = 0; r < 16; r++) { y0[r] = 0.f; y1[r] = 0.f; }

        const int nt = (qt >> 1) + 1;  // tiles of 64 = ceil((qt+1)/2); last contains diagonal

        // prologue: stage K(0) -> lK[0] (8 x gload16)
#pragma unroll
        for (int i = 0; i < 8; i++) {
            int s = i * 64 + lane;
            int row = s >> 3;
            int gc = ((s & 7) ^ (row & 7)) * 8;
            gload16(Kb + (size_t)row * 64 + gc, &lK[0][i * 512]);
        }

        for (int it = 0; it < nt; it += 2) {
            attn_tile64(it * 64, it == nt - 1, it + 1 < nt, lane, hi, ln, qw, Kb, Vb,
                        &lK[0][0], &lK[1][0], qf, mrun, lpart, y0, y1);
            if (it + 1 < nt)
                attn_tile64((it + 1) * 64, it + 1 == nt - 1, it + 2 < nt, lane, hi, ln, qw,
                            Kb, Vb, &lK[1][0], &lK[0][0], qf, mrun, lpart, y0, y1);
        }

        // phase epilogue: combine half-lane partials, normalize, store
        float lT = lpart + __shfl_xor(lpart, 32);
        float inv = 1.0f / lT;
#pragma unroll
        for (int r = 0; r < 16; r++) {
            int crow = (r & 3) + 8 * (r >> 2) + 4 * hi;
            float invr = __shfl(inv, crow);
            size_t base = ((size_t)(b * 2048 + qw + crow)) * 1024 + hh * 64 + ln;
            O[base] = (f16)(y0[r] * invr);
            O[base + 32] = (f16)(y1[r] * invr);
        }
    }
}

// ---------------- launch ----------------

extern "C" void kernel_launch(void* const* d_in, const int* in_sizes, int n_in,
                              void* d_out, int out_size, void* d_ws, size_t ws_size,
                              hipStream_t stream) {
    const float* x      = (const float*)d_in[0];
    const float* W_attn = (const float*)d_in[1];
    const float* b_attn = (const float*)d_in[2];
    const float* W_proj = (const float*)d_in[3];
    const float* b_proj = (const float*)d_in[4];
    float* out = (float*)d_out;

    char* ws = (char*)d_ws;
    f16* xb  = (f16*)ws;                                   // 16 MB (reused as attn out)
    f16* Wat = (f16*)(ws + 16777216);                      // 6 MB
    f16* Wpt = (f16*)(ws + 16777216 + 6291456);            // 2 MB
    f16* Vt  = (f16*)(ws + 16777216 + 6291456 + 2097152);  // 16 MB
    f16* Qs  = (f16*)d_out;                                // scratch: first 16 MB of out
    f16* Ks  = (f16*)((char*)d_out + 16777216);            // scratch: second 16 MB of out

    cvt_f16_kernel<<<4096, 256, 0, stream>>>(x, xb, 1048576);
    transpose_cvt<<<dim3(96, 32), dim3(32, 8), 0, stream>>>(W_attn, Wat, 1024, 3072);
    transpose_cvt<<<dim3(32, 32), dim3(32, 8), 0, stream>>>(W_proj, Wpt, 1024, 1024);
    qkv_gemm<<<1536, 256, 0, stream>>>(xb, Wat, b_attn, Qs, Ks, Vt);
    attn_kernel<<<2048, 64, 0, stream>>>(Qs, Ks, Vt, xb);
    proj_gemm<<<512, 256, 0, stream>>>(xb, Wpt, b_proj, out);
}

// Round 16
// 238.057 us; speedup vs baseline: 1.0148x; 1.0148x over previous
//
#include <hip/hip_runtime.h>

typedef _Float16 f16;
typedef __attribute__((ext_vector_type(8))) _Float16 h8;
typedef __attribute__((ext_vector_type(4))) _Float16 h4;
typedef __attribute__((ext_vector_type(4))) float f4;
typedef __attribute__((ext_vector_type(16))) float f16x;
typedef __attribute__((ext_vector_type(4))) unsigned u4;

#define MFMA(a, b, c) __builtin_amdgcn_mfma_f32_16x16x32_f16(a, b, c, 0, 0, 0)
#define MFMA32(a, b, c) __builtin_amdgcn_mfma_f32_32x32x16_f16(a, b, c, 0, 0, 0)

// Q prescale: 1/sqrt(64) * log2(e), folded into qkv epilogue -> softmax in base-2
#define QSCALE 0.18033688011112042f

__device__ __forceinline__ void gload16(const void* g, void* l) {
    __builtin_amdgcn_global_load_lds((const __attribute__((address_space(1))) void*)g,
                                     (__attribute__((address_space(3))) void*)l, 16, 0, 0);
}

__device__ __forceinline__ float fexp2(float x) {
    float r;
    asm("v_exp_f32 %0, %1" : "=v"(r) : "v"(x));
    return r;
}

// pack 2 f32 -> 2 f16 (RTZ) in one u32
__device__ __forceinline__ unsigned pkh(float a, float b) {
    auto r = __builtin_amdgcn_cvt_pkrtz(a, b);  // __fp16 ext_vector(2)
    return __builtin_bit_cast(unsigned, r);
}

// v_permlane32_swap_b32: a[l>=32] <-> b[l<32]  (both operands modified)
__device__ __forceinline__ void plswap(unsigned& a, unsigned& b) {
    asm volatile("v_permlane32_swap_b32 %0, %1" : "+v"(a), "+v"(b));
}

// ---------------- conversion kernels ----------------

__global__ __launch_bounds__(256) void cvt_f16_kernel(const float* __restrict__ in,
                                                      f16* __restrict__ out, int n8) {
    int i = blockIdx.x * blockDim.x + threadIdx.x;
    if (i >= n8) return;
    const float4* p = (const float4*)in + (size_t)i * 2;
    float4 a = p[0], b = p[1];
    h8 o;
    o[0] = (f16)a.x; o[1] = (f16)a.y; o[2] = (f16)a.z; o[3] = (f16)a.w;
    o[4] = (f16)b.x; o[5] = (f16)b.y; o[6] = (f16)b.z; o[7] = (f16)b.w;
    *((h8*)out + i) = o;
}

// in: [R][Cc] f32 row-major -> out: [Cc][R] f16 row-major
__global__ __launch_bounds__(256) void transpose_cvt(const float* __restrict__ in,
                                                     f16* __restrict__ out, int R, int Cc) {
    __shared__ float tile[32][33];
    int tx = threadIdx.x, ty = threadIdx.y;
    int c0 = blockIdx.x * 32, r0 = blockIdx.y * 32;
#pragma unroll
    for (int k = 0; k < 32; k += 8)
        tile[ty + k][tx] = in[(size_t)(r0 + ty + k) * Cc + c0 + tx];
    __syncthreads();
#pragma unroll
    for (int k = 0; k < 32; k += 8)
        out[(size_t)(c0 + ty + k) * R + r0 + tx] = (f16)tile[tx][ty + k];
}

// ---------------- GEMM core (128x128 tile, BK=64, 4 waves, swizzled LDS) ----------------

__device__ __forceinline__ void gemm_core(const f16* __restrict__ A, const f16* __restrict__ Bt,
                                          int K, int m0, int n0,
                                          f16* lA, f16* lB, f4 acc[4][4]) {
    const int tid = threadIdx.x, lane = tid & 63, wave = tid >> 6;
    const int wm = (wave >> 1) * 64, wn = (wave & 1) * 64;
    for (int k0 = 0; k0 < K; k0 += 64) {
        __syncthreads();
#pragma unroll
        for (int i = 0; i < 4; i++) {
            int s = i * 256 + wave * 64 + lane;
            int row = s >> 3;
            int gc = ((s & 7) ^ (row & 7)) * 8;
            gload16(A + (size_t)(m0 + row) * K + k0 + gc, lA + (i * 256 + wave * 64) * 8);
        }
#pragma unroll
        for (int i = 0; i < 4; i++) {
            int s = i * 256 + wave * 64 + lane;
            int row = s >> 3;
            int gc = ((s & 7) ^ (row & 7)) * 8;
            gload16(Bt + (size_t)(n0 + row) * K + k0 + gc, lB + (i * 256 + wave * 64) * 8);
        }
        __syncthreads();
#pragma unroll
        for (int kk = 0; kk < 2; kk++) {
            h8 af[4], bg[4];
#pragma unroll
            for (int im = 0; im < 4; im++) {
                int row = wm + im * 16 + (lane & 15);
                int pc = (kk * 4 + (lane >> 4)) ^ (row & 7);
                af[im] = *(const h8*)(lA + row * 64 + pc * 8);
            }
#pragma unroll
            for (int in = 0; in < 4; in++) {
                int row = wn + in * 16 + (lane & 15);
                int pc = (kk * 4 + (lane >> 4)) ^ (row & 7);
                bg[in] = *(const h8*)(lB + row * 64 + pc * 8);
            }
#pragma unroll
            for (int im = 0; im < 4; im++)
#pragma unroll
                for (int in = 0; in < 4; in++)
                    acc[im][in] = MFMA(af[im], bg[in], acc[im][in]);
        }
    }
}

// ---------------- QKV GEMM: writes Q (prescaled), K [BH][T][64], V^T [BH][64][T] ----------------

__global__ __launch_bounds__(256) void qkv_gemm(const f16* __restrict__ A, const f16* __restrict__ Bt,
                                                const float* __restrict__ bias,
                                                f16* __restrict__ Qo, f16* __restrict__ Ko,
                                                f16* __restrict__ Vo) {
    __shared__ f16 lA[128 * 64], lB[128 * 64];
    f4 acc[4][4];
    const f4 zz = {0.f, 0.f, 0.f, 0.f};
#pragma unroll
    for (int i = 0; i < 4; i++)
#pragma unroll
        for (int j = 0; j < 4; j++) acc[i][j] = zz;

    const int swz = (blockIdx.x & 7) * 192 + (blockIdx.x >> 3);  // XCD-chunked (1536 = 8*192)
    const int nb = swz % 24, mb = swz / 24;
    gemm_core(A, Bt, 1024, mb * 128, nb * 128, lA, lB, acc);

    const int lane = threadIdx.x & 63, wave = threadIdx.x >> 6;
    const int wm = (wave >> 1) * 64, wn = (wave & 1) * 64;
#pragma unroll
    for (int im = 0; im < 4; im++) {
        int m4 = mb * 128 + wm + im * 16 + (lane >> 4) * 4;
        int b = m4 >> 11, t0 = m4 & 2047;
#pragma unroll
        for (int in = 0; in < 4; in++) {
            int n = nb * 128 + wn + in * 16 + (lane & 15);
            float bb = bias[n];
            int sec = n >> 10, cc = n & 1023, hh = cc >> 6, d = cc & 63;
            if (sec == 2) {
                h4 pv;
#pragma unroll
                for (int r = 0; r < 4; r++) pv[r] = (f16)(acc[im][in][r] + bb);
                *(h4*)(Vo + ((size_t)(b * 16 + hh) * 64 + d) * 2048 + t0) = pv;
            } else {
                f16* dst = sec ? Ko : Qo;
                float sc = sec ? 1.0f : QSCALE;  // Q prescaled for base-2 softmax
                size_t base = ((size_t)(b * 16 + hh) * 2048 + t0) * 64 + d;
#pragma unroll
                for (int r = 0; r < 4; r++)
                    dst[base + (size_t)r * 64] = (f16)((acc[im][in][r] + bb) * sc);
            }
        }
    }
}

// ---------------- Proj GEMM: f32 output + bias ----------------

__global__ __launch_bounds__(256) void proj_gemm(const f16* __restrict__ A, const f16* __restrict__ Bt,
                                                 const float* __restrict__ bias,
                                                 float* __restrict__ out) {
    __shared__ f16 lA[128 * 64], lB[128 * 64];
    f4 acc[4][4];
    const f4 zz = {0.f, 0.f, 0.f, 0.f};
#pragma unroll
    for (int i = 0; i < 4; i++)
#pragma unroll
        for (int j = 0; j < 4; j++) acc[i][j] = zz;

    const int swz = (blockIdx.x & 7) * 64 + (blockIdx.x >> 3);  // XCD-chunked (512 = 8*64)
    const int nb = swz & 7, mb = swz >> 3;
    gemm_core(A, Bt, 1024, mb * 128, nb * 128, lA, lB, acc);

    const int lane = threadIdx.x & 63, wave = threadIdx.x >> 6;
    const int wm = (wave >> 1) * 64, wn = (wave & 1) * 64;
#pragma unroll
    for (int im = 0; im < 4; im++) {
        int m4 = mb * 128 + wm + im * 16 + (lane >> 4) * 4;
#pragma unroll
        for (int in = 0; in < 4; in++) {
            int n = nb * 128 + wn + in * 16 + (lane & 15);
            float bb = bias[n];
#pragma unroll
            for (int r = 0; r < 4; r++)
                out[(size_t)(m4 + r) * 1024 + n] = acc[im][in][r] + bb;
        }
    }
}

// ---------------- Flash attention: 2-wave blocks, split-K + in-block combine ----------------
// Q(prescaled),K: [BH][2048][64] f16; Vg: [BH][64][2048] f16 (transposed); O: [B][2048][1024] f16
// Grid 2048 x 128 threads. Block p handles q-tiles (63-p) then (p). Per phase, the TWO
// waves split the K-range: wave0 tiles [0,h), wave1 [h,nt), h=ceil(nt/2) -> per-wave work
// = 33/32 tiles for EVERY p (uniform) and residency = 16 waves/CU (= capacity at VGPR~124;
// R14's uniform grid used only 8). Flash partials (m,l,y) combined in-block: wave0 publishes
// its 8KB y + (m,l) through its own finished K-LDS region, one barrier, wave1 merges+stores.
// Wave loop bodies are R14's proven zero-barrier tile: private K-LDS double-buffer via
// global_load_lds, V->named reg sets one tile ahead, vmcnt(8); swapped QK^T (mfma_32x32x16),
// in-register base-2 softmax with defer-max, P->A via cvt_pkrtz+permlane32_swap (HW-verified).

#define ASM_VMCNT(N) asm volatile("s_waitcnt vmcnt(" #N ")" ::: "memory")

__device__ __forceinline__ void attn_tile(int k0, bool last, bool stage_next,
                                          int lane, int hi, int ln,
                                          const f16* __restrict__ Kb, const f16* __restrict__ Vb,
                                          const f16* lKcur, f16* lKnxt,
                                          const h8 (&qf)[4], h8 (&vf)[2][2], h8 (&vfn)[2][2],
                                          float& mrun, float& lpart, f16x& y0, f16x& y1) {
    if (stage_next) {
        // K(it+1) -> other LDS buffer (4 x gload16)
#pragma unroll
        for (int i = 0; i < 4; i++) {
            int s = i * 64 + lane;
            int row = s >> 3;
            int gc = ((s & 7) ^ (row & 7)) * 8;
            gload16(Kb + (size_t)(k0 + 32 + row) * 64 + gc, lKnxt + i * 512);
        }
        // V(it+1) -> other register set (4 x dwordx4)
#pragma unroll
        for (int ks = 0; ks < 2; ks++)
#pragma unroll
            for (int j = 0; j < 2; j++)
                vfn[ks][j] = *(const h8*)(Vb + (size_t)(j * 32 + ln) * 2048 + (k0 + 32) +
                                          ks * 16 + hi * 8);
        ASM_VMCNT(8);  // wait only last tile's 8 loads; current 8 stay in flight
    } else {
        ASM_VMCNT(0);
    }
    __builtin_amdgcn_sched_barrier(0);

    // S^T = K.Q^T (A = K rows from LDS, B = Q regs); lane owns q = qw+ln
    f16x s0;
#pragma unroll
    for (int r = 0; r < 16; r++) s0[r] = 0.f;
    __builtin_amdgcn_s_setprio(1);
#pragma unroll
    for (int dd = 0; dd < 4; dd++) {
        const int c = (dd * 2 + hi) ^ (ln & 7);  // swizzled 16B-chunk index
        h8 ka = *(const h8*)(lKcur + ln * 64 + c * 8);
        s0 = MFMA32(ka, qf[dd], s0);
    }
    __builtin_amdgcn_s_setprio(0);

    if (last) {  // diagonal tile (k0 == qw): mask k-local kl > ln
#pragma unroll
        for (int r = 0; r < 16; r++) {
            int kl = (r & 3) + 8 * (r >> 2) + 4 * hi;
            if (kl > ln) s0[r] = -3e38f;
        }
    }

    // register-local softmax (base-2, defer-max)
    float vmax = s0[0];
#pragma unroll
    for (int r = 1; r < 16; r++) vmax = fmaxf(vmax, s0[r]);
    vmax = fmaxf(vmax, __shfl_xor(vmax, 32));
    if (!__all(vmax <= mrun + 8.0f)) {
        float mnew = fmaxf(mrun, vmax);
        float sc = fexp2(mrun - mnew);
        lpart *= sc;
        mrun = mnew;
#pragma unroll
        for (int r = 0; r < 16; r++) {
            float scy = __shfl(sc, (r & 3) + 8 * (r >> 2) + 4 * hi);
            y0[r] *= scy;
            y1[r] *= scy;
        }
    }
    float ls = 0.f;
#pragma unroll
    for (int r = 0; r < 16; r++) {
        float p = fexp2(s0[r] - mrun);
        s0[r] = p;
        ls += p;
    }
    lpart += ls;

    // P -> PV A-fragments: 8 cvt_pk + 4 permlane32_swap (no LDS; verified R9)
    h8 pa[2];
    {
        unsigned a0 = pkh(s0[0], s0[1]), a1 = pkh(s0[2], s0[3]);
        unsigned b0 = pkh(s0[4], s0[5]), b1 = pkh(s0[6], s0[7]);
        plswap(a0, b0); plswap(a1, b1);
        u4 w0; w0[0] = a0; w0[1] = a1; w0[2] = b0; w0[3] = b1;
        pa[0] = __builtin_bit_cast(h8, w0);
        unsigned c0 = pkh(s0[8], s0[9]), c1 = pkh(s0[10], s0[11]);
        unsigned d0 = pkh(s0[12], s0[13]), d1 = pkh(s0[14], s0[15]);
        plswap(c0, d0); plswap(c1, d1);
        u4 w1; w1[0] = c0; w1[1] = c1; w1[2] = d0; w1[3] = d1;
        pa[1] = __builtin_bit_cast(h8, w1);
    }

    // Y += P V  (V prefetched into regs one tile ago; no wait needed)
    __builtin_amdgcn_s_setprio(1);
#pragma unroll
    for (int ks = 0; ks < 2; ks++) {
        y0 = MFMA32(pa[ks], vf[ks][0], y0);
        y1 = MFMA32(pa[ks], vf[ks][1], y1);
    }
    __builtin_amdgcn_s_setprio(0);
}

__global__ __launch_bounds__(128) void attn_kernel(const f16* __restrict__ Q,
                                                   const f16* __restrict__ K,
                                                   const f16* __restrict__ Vg,
                                                   f16* __restrict__ O) {
    __shared__ f16 lK[2][2][2048];  // [wave][buf][32 rows x 64]
    __shared__ float xml[2][64];    // wave0's (m, l) per lane
    const int tid = threadIdx.x, lane = tid & 63, wave = tid >> 6;
    const int hi = lane >> 5, ln = lane & 31;
    const int bh = blockIdx.x & 63;
    const int p = (int)(blockIdx.x >> 6);  // 0..31
    const f16* Qb = Q + (size_t)bh * 2048 * 64;
    const f16* Kb = K + (size_t)bh * 2048 * 64;
    const f16* Vb = Vg + (size_t)bh * 64 * 2048;
    const int b = bh >> 4, hh = bh & 15;
    f16* myK = &lK[wave][0][0];

    for (int ph = 0; ph < 2; ph++) {
        const int qt = ph ? p : 63 - p;  // complementary pair
        const int qw = qt * 32;
        const int nt = qt + 1;           // total K-tiles of 32 for this q-tile
        const int h = (nt + 1) >> 1;     // wave0: [0,h), wave1: [h,nt) -> 33/32 per wave total
        const int gs = wave ? h : 0;
        const int ge = wave ? nt : h;

        // hoist Q fragments (B-operand): Q[qw+ln][dd*16 + hi*8 .. +8]
        h8 qf[4];
#pragma unroll
        for (int dd = 0; dd < 4; dd++)
            qf[dd] = *(const h8*)(Qb + (size_t)(qw + ln) * 64 + dd * 16 + hi * 8);

        float mrun = -3e38f, lpart = 0.f;
        f16x y0, y1;
#pragma unroll
        for (int r = 0; r < 16; r++) { y0[r] = 0.f; y1[r] = 0.f; }

        h8 vfA[2][2], vfB[2][2];
        if (gs < ge) {
            // prologue: stage K(gs) -> buf0, V(gs) -> vfA  (4 + 4 VMEM ops)
#pragma unroll
            for (int i = 0; i < 4; i++) {
                int s = i * 64 + lane;
                int row = s >> 3;
                int gc = ((s & 7) ^ (row & 7)) * 8;
                gload16(Kb + (size_t)(gs * 32 + row) * 64 + gc, myK + i * 512);
            }
#pragma unroll
            for (int ks = 0; ks < 2; ks++)
#pragma unroll
                for (int j = 0; j < 2; j++)
                    vfA[ks][j] = *(const h8*)(Vb + (size_t)(j * 32 + ln) * 2048 + gs * 32 +
                                              ks * 16 + hi * 8);

            for (int g = gs; g < ge; g += 2) {
                attn_tile(g * 32, g == nt - 1, g + 1 < ge, lane, hi, ln, Kb, Vb,
                          myK, myK + 2048, qf, vfA, vfB, mrun, lpart, y0, y1);
                if (g + 1 < ge)
                    attn_tile((g + 1) * 32, g + 1 == nt - 1, g + 2 < ge, lane, hi, ln, Kb, Vb,
                              myK + 2048, myK, qf, vfB, vfA, mrun, lpart, y0, y1);
            }
        }

        // ---- in-block split-K combine ----
        float lT = lpart + __shfl_xor(lpart, 32);  // per-row l (row-uniform across hi)
        float* yb = (float*)&lK[0][0][0];          // wave0's finished K region = 8KB
        if (wave == 0) {
#pragma unroll
            for (int r = 0; r < 16; r++) {
                yb[r * 64 + lane] = y0[r];          // conflict-free: lane-contiguous
                yb[1024 + r * 64 + lane] = y1[r];
            }
            xml[0][lane] = mrun;
            xml[1][lane] = lT;
        }
        __syncthreads();
        if (wave == 1) {
            float m0 = xml[0][lane], l0 = xml[1][lane];
            float m = fmaxf(m0, mrun);
            float a0 = fexp2(m0 - m), a1 = fexp2(mrun - m);
            float inv = 1.0f / (l0 * a0 + lT * a1);
#pragma unroll
            for (int r = 0; r < 16; r++) {
                int crow = (r & 3) + 8 * (r >> 2) + 4 * hi;
                float a0r = __shfl(a0, crow);
                float a1r = __shfl(a1, crow);
                float invr = __shfl(inv, crow);
                size_t base = ((size_t)(b * 2048 + qw + crow)) * 1024 + hh * 64 + ln;
                O[base] = (f16)((yb[r * 64 + lane] * a0r + y0[r] * a1r) * invr);
                O[base + 32] = (f16)((yb[1024 + r * 64 + lane] * a0r + y1[r] * a1r) * invr);
            }
        }
        __syncthreads();  // wave1 done reading yb before next phase restages K there
    }
}

// ---------------- launch ----------------

extern "C" void kernel_launch(void* const* d_in, const int* in_sizes, int n_in,
                              void* d_out, int out_size, void* d_ws, size_t ws_size,
                              hipStream_t stream) {
    const float* x      = (const float*)d_in[0];
    const float* W_attn = (const float*)d_in[1];
    const float* b_attn = (const float*)d_in[2];
    const float* W_proj = (const float*)d_in[3];
    const float* b_proj = (const float*)d_in[4];
    float* out = (float*)d_out;

    char* ws = (char*)d_ws;
    f16* xb  = (f16*)ws;                                   // 16 MB (reused as attn out)
    f16* Wat = (f16*)(ws + 16777216);                      // 6 MB
    f16* Wpt = (f16*)(ws + 16777216 + 6291456);            // 2 MB
    f16* Vt  = (f16*)(ws + 16777216 + 6291456 + 2097152);  // 16 MB
    f16* Qs  = (f16*)d_out;                                // scratch: first 16 MB of out
    f16* Ks  = (f16*)((char*)d_out + 16777216);            // scratch: second 16 MB of out

    cvt_f16_kernel<<<4096, 256, 0, stream>>>(x, xb, 1048576);
    transpose_cvt<<<dim3(96, 32), dim3(32, 8), 0, stream>>>(W_attn, Wat, 1024, 3072);
    transpose_cvt<<<dim3(32, 32), dim3(32, 8), 0, stream>>>(W_proj, Wpt, 1024, 1024);
    qkv_gemm<<<1536, 256, 0, stream>>>(xb, Wat, b_attn, Qs, Ks, Vt);
    attn_kernel<<<2048, 128, 0, stream>>>(Qs, Ks, Vt, xb);
    proj_gemm<<<512, 256, 0, stream>>>(xb, Wpt, b_proj, out);
}

// Round 18
// 206.013 us; speedup vs baseline: 1.1727x; 1.1555x over previous
//
#include <hip/hip_runtime.h>

typedef _Float16 f16;
typedef __attribute__((ext_vector_type(8))) _Float16 h8;
typedef __attribute__((ext_vector_type(4))) _Float16 h4;
typedef __attribute__((ext_vector_type(8))) short s8;     // 8 bf16 (4 VGPRs)
typedef __attribute__((ext_vector_type(4))) unsigned short u16x4;
typedef __attribute__((ext_vector_type(4))) float f4;
typedef __attribute__((ext_vector_type(16))) float f16x;
typedef __attribute__((ext_vector_type(4))) unsigned u4;

#define MFMA(a, b, c) __builtin_amdgcn_mfma_f32_16x16x32_f16(a, b, c, 0, 0, 0)
#define MFMA32(a, b, c) __builtin_amdgcn_mfma_f32_32x32x16_f16(a, b, c, 0, 0, 0)
#define MFMA32B(a, b, c) __builtin_amdgcn_mfma_f32_32x32x16_bf16(a, b, c, 0, 0, 0)

// Q prescale: 1/sqrt(64) * log2(e), folded into qkv epilogue -> softmax in base-2
#define QSCALE 0.18033688011112042f

__device__ __forceinline__ void gload16(const void* g, void* l) {
    __builtin_amdgcn_global_load_lds((const __attribute__((address_space(1))) void*)g,
                                     (__attribute__((address_space(3))) void*)l, 16, 0, 0);
}

__device__ __forceinline__ float fexp2(float x) {
    float r;
    asm("v_exp_f32 %0, %1" : "=v"(r) : "v"(x));
    return r;
}

// pack 2 f32 -> 2 bf16 in one u32 (low = src0)
__device__ __forceinline__ unsigned pkb(float a, float b) {
    unsigned r;
    asm("v_cvt_pk_bf16_f32 %0, %1, %2" : "=v"(r) : "v"(a), "v"(b));
    return r;
}

// f32 -> bf16 with round-to-nearest-even
__device__ __forceinline__ unsigned short bf16rn(float x) {
    unsigned u = __builtin_bit_cast(unsigned, x);
    u += 0x7fffu + ((u >> 16) & 1u);
    return (unsigned short)(u >> 16);
}

// v_permlane32_swap_b32: a[l>=32] <-> b[l<32]  (both operands modified)
__device__ __forceinline__ void plswap(unsigned& a, unsigned& b) {
    asm volatile("v_permlane32_swap_b32 %0, %1" : "+v"(a), "+v"(b));
}

// ---------------- conversion kernels ----------------

__global__ __launch_bounds__(256) void cvt_f16_kernel(const float* __restrict__ in,
                                                      f16* __restrict__ out, int n8) {
    int i = blockIdx.x * blockDim.x + threadIdx.x;
    if (i >= n8) return;
    const float4* p = (const float4*)in + (size_t)i * 2;
    float4 a = p[0], b = p[1];
    h8 o;
    o[0] = (f16)a.x; o[1] = (f16)a.y; o[2] = (f16)a.z; o[3] = (f16)a.w;
    o[4] = (f16)b.x; o[5] = (f16)b.y; o[6] = (f16)b.z; o[7] = (f16)b.w;
    *((h8*)out + i) = o;
}

// in: [R][Cc] f32 row-major -> out: [Cc][R] f16 row-major
__global__ __launch_bounds__(256) void transpose_cvt(const float* __restrict__ in,
                                                     f16* __restrict__ out, int R, int Cc) {
    __shared__ float tile[32][33];
    int tx = threadIdx.x, ty = threadIdx.y;
    int c0 = blockIdx.x * 32, r0 = blockIdx.y * 32;
#pragma unroll
    for (int k = 0; k < 32; k += 8)
        tile[ty + k][tx] = in[(size_t)(r0 + ty + k) * Cc + c0 + tx];
    __syncthreads();
#pragma unroll
    for (int k = 0; k < 32; k += 8)
        out[(size_t)(c0 + ty + k) * R + r0 + tx] = (f16)tile[tx][ty + k];
}

// ---------------- GEMM core (128x128 tile, BK=64, 4 waves, swizzled LDS) ----------------

__device__ __forceinline__ void gemm_core(const f16* __restrict__ A, const f16* __restrict__ Bt,
                                          int K, int m0, int n0,
                                          f16* lA, f16* lB, f4 acc[4][4]) {
    const int tid = threadIdx.x, lane = tid & 63, wave = tid >> 6;
    const int wm = (wave >> 1) * 64, wn = (wave & 1) * 64;
    for (int k0 = 0; k0 < K; k0 += 64) {
        __syncthreads();
#pragma unroll
        for (int i = 0; i < 4; i++) {
            int s = i * 256 + wave * 64 + lane;
            int row = s >> 3;
            int gc = ((s & 7) ^ (row & 7)) * 8;
            gload16(A + (size_t)(m0 + row) * K + k0 + gc, lA + (i * 256 + wave * 64) * 8);
        }
#pragma unroll
        for (int i = 0; i < 4; i++) {
            int s = i * 256 + wave * 64 + lane;
            int row = s >> 3;
            int gc = ((s & 7) ^ (row & 7)) * 8;
            gload16(Bt + (size_t)(n0 + row) * K + k0 + gc, lB + (i * 256 + wave * 64) * 8);
        }
        __syncthreads();
#pragma unroll
        for (int kk = 0; kk < 2; kk++) {
            h8 af[4], bg[4];
#pragma unroll
            for (int im = 0; im < 4; im++) {
                int row = wm + im * 16 + (lane & 15);
                int pc = (kk * 4 + (lane >> 4)) ^ (row & 7);
                af[im] = *(const h8*)(lA + row * 64 + pc * 8);
            }
#pragma unroll
            for (int in = 0; in < 4; in++) {
                int row = wn + in * 16 + (lane & 15);
                int pc = (kk * 4 + (lane >> 4)) ^ (row & 7);
                bg[in] = *(const h8*)(lB + row * 64 + pc * 8);
            }
#pragma unroll
            for (int im = 0; im < 4; im++)
#pragma unroll
                for (int in = 0; in < 4; in++)
                    acc[im][in] = MFMA(af[im], bg[in], acc[im][in]);
        }
    }
}

// ---------------- QKV GEMM: Q (prescaled), K [BH][T][64] f16; V^T [BH][64][T] bf16 ----------------

__global__ __launch_bounds__(256) void qkv_gemm(const f16* __restrict__ A, const f16* __restrict__ Bt,
                                                const float* __restrict__ bias,
                                                f16* __restrict__ Qo, f16* __restrict__ Ko,
                                                unsigned short* __restrict__ Vo) {
    __shared__ f16 lA[128 * 64], lB[128 * 64];
    f4 acc[4][4];
    const f4 zz = {0.f, 0.f, 0.f, 0.f};
#pragma unroll
    for (int i = 0; i < 4; i++)
#pragma unroll
        for (int j = 0; j < 4; j++) acc[i][j] = zz;

    const int swz = (blockIdx.x & 7) * 192 + (blockIdx.x >> 3);  // XCD-chunked (1536 = 8*192)
    const int nb = swz % 24, mb = swz / 24;
    gemm_core(A, Bt, 1024, mb * 128, nb * 128, lA, lB, acc);

    const int lane = threadIdx.x & 63, wave = threadIdx.x >> 6;
    const int wm = (wave >> 1) * 64, wn = (wave & 1) * 64;
#pragma unroll
    for (int im = 0; im < 4; im++) {
        int m4 = mb * 128 + wm + im * 16 + (lane >> 4) * 4;
        int b = m4 >> 11, t0 = m4 & 2047;
#pragma unroll
        for (int in = 0; in < 4; in++) {
            int n = nb * 128 + wn + in * 16 + (lane & 15);
            float bb = bias[n];
            int sec = n >> 10, cc = n & 1023, hh = cc >> 6, d = cc & 63;
            if (sec == 2) {
                u16x4 pv;
#pragma unroll
                for (int r = 0; r < 4; r++) pv[r] = bf16rn(acc[im][in][r] + bb);
                *(u16x4*)(Vo + ((size_t)(b * 16 + hh) * 64 + d) * 2048 + t0) = pv;
            } else {
                f16* dst = sec ? Ko : Qo;
                float sc = sec ? 1.0f : QSCALE;  // Q prescaled for base-2 softmax
                size_t base = ((size_t)(b * 16 + hh) * 2048 + t0) * 64 + d;
#pragma unroll
                for (int r = 0; r < 4; r++)
                    dst[base + (size_t)r * 64] = (f16)((acc[im][in][r] + bb) * sc);
            }
        }
    }
}

// ---------------- Proj GEMM: f32 output + bias ----------------

__global__ __launch_bounds__(256) void proj_gemm(const f16* __restrict__ A, const f16* __restrict__ Bt,
                                                 const float* __restrict__ bias,
                                                 float* __restrict__ out) {
    __shared__ f16 lA[128 * 64], lB[128 * 64];
    f4 acc[4][4];
    const f4 zz = {0.f, 0.f, 0.f, 0.f};
#pragma unroll
    for (int i = 0; i < 4; i++)
#pragma unroll
        for (int j = 0; j < 4; j++) acc[i][j] = zz;

    const int swz = (blockIdx.x & 7) * 64 + (blockIdx.x >> 3);  // XCD-chunked (512 = 8*64)
    const int nb = swz & 7, mb = swz >> 3;
    gemm_core(A, Bt, 1024, mb * 128, nb * 128, lA, lB, acc);

    const int lane = threadIdx.x & 63, wave = threadIdx.x >> 6;
    const int wm = (wave >> 1) * 64, wn = (wave & 1) * 64;
#pragma unroll
    for (int im = 0; im < 4; im++) {
        int m4 = mb * 128 + wm + im * 16 + (lane >> 4) * 4;
#pragma unroll
        for (int in = 0; in < 4; in++) {
            int n = nb * 128 + wn + in * 16 + (lane & 15);
            float bb = bias[n];
#pragma unroll
            for (int r = 0; r < 4; r++)
                out[(size_t)(m4 + r) * 1024 + n] = acc[im][in][r] + bb;
        }
    }
}

// ---------------- Flash attention: 1-wave blocks, pairs, NO-SHIFT softmax via bf16 P ----------------
// Q(prescaled),K: [BH][2048][64] f16; Vg: [BH][64][2048] BF16 (transposed); O: [B][2048][1024] f16
// Grid 2048 x 64 threads: block p does q-tiles (63-p) then (p); uniform 65 tiles/block;
// 8 blocks/CU flat; waves fully independent (zero barriers). R14 packaging (proven best).
// Softmax: P = 2^S with NO shift and NO online max (shift-invariance). R17's f16-subnormal
// failure is fixed by keeping P in BF16 (f32-range exponent -> scale-invariant precision);
// PV uses mfma_f32_32x32x16_bf16 (C/D layout dtype-independent, m89/m101). S bounded ~|12|
// -> p <= 2^17, l <= 2^28: no overflow. Entire max machinery deleted correctly this time.
// Per tile: stage K(it+1)->LDS + V(it+1)->named regs, vmcnt(8) waits only last tile's loads.

#define ASM_VMCNT(N) asm volatile("s_waitcnt vmcnt(" #N ")" ::: "memory")

__device__ __forceinline__ void attn_tile(int k0, bool last, bool stage_next,
                                          int lane, int hi, int ln,
                                          const f16* __restrict__ Kb,
                                          const unsigned short* __restrict__ Vb,
                                          const f16* lKcur, f16* lKnxt,
                                          const h8 (&qf)[4], s8 (&vf)[2][2], s8 (&vfn)[2][2],
                                          float& lpart, f16x& y0, f16x& y1) {
    if (stage_next) {
        // K(it+1) -> other LDS buffer (4 x gload16)
#pragma unroll
        for (int i = 0; i < 4; i++) {
            int s = i * 64 + lane;
            int row = s >> 3;
            int gc = ((s & 7) ^ (row & 7)) * 8;
            gload16(Kb + (size_t)(k0 + 32 + row) * 64 + gc, lKnxt + i * 512);
        }
        // V(it+1) -> other register set (4 x dwordx4)
#pragma unroll
        for (int ks = 0; ks < 2; ks++)
#pragma unroll
            for (int j = 0; j < 2; j++)
                vfn[ks][j] = *(const s8*)(Vb + (size_t)(j * 32 + ln) * 2048 + (k0 + 32) +
                                          ks * 16 + hi * 8);
        ASM_VMCNT(8);  // wait only last tile's 8 loads; current 8 stay in flight
    } else {
        ASM_VMCNT(0);
    }
    __builtin_amdgcn_sched_barrier(0);

    // S^T = K.Q^T (A = K rows from LDS, B = Q regs); lane owns q = qw+ln
    f16x s0;
#pragma unroll
    for (int r = 0; r < 16; r++) s0[r] = 0.f;
    __builtin_amdgcn_s_setprio(1);
#pragma unroll
    for (int dd = 0; dd < 4; dd++) {
        const int c = (dd * 2 + hi) ^ (ln & 7);  // swizzled 16B-chunk index
        h8 ka = *(const h8*)(lKcur + ln * 64 + c * 8);
        s0 = MFMA32(ka, qf[dd], s0);
    }
    __builtin_amdgcn_s_setprio(0);

    if (last) {  // diagonal tile (k0 == qw): mask k-local kl > ln
#pragma unroll
        for (int r = 0; r < 16; r++) {
            int kl = (r & 3) + 8 * (r >> 2) + 4 * hi;
            if (kl > ln) s0[r] = -3e38f;
        }
    }

    // no-shift softmax: P = 2^S (bf16 keeps relative precision at any scale)
    float ls = 0.f;
#pragma unroll
    for (int r = 0; r < 16; r++) {
        float p = fexp2(s0[r]);
        s0[r] = p;
        ls += p;
    }
    lpart += ls;

    // P -> PV A-fragments (bf16): 8 cvt_pk_bf16 + 4 permlane32_swap (layout as R9)
    s8 pa[2];
    {
        unsigned a0 = pkb(s0[0], s0[1]), a1 = pkb(s0[2], s0[3]);
        unsigned b0 = pkb(s0[4], s0[5]), b1 = pkb(s0[6], s0[7]);
        plswap(a0, b0); plswap(a1, b1);
        u4 w0; w0[0] = a0; w0[1] = a1; w0[2] = b0; w0[3] = b1;
        pa[0] = __builtin_bit_cast(s8, w0);
        unsigned c0 = pkb(s0[8], s0[9]), c1 = pkb(s0[10], s0[11]);
        unsigned d0 = pkb(s0[12], s0[13]), d1 = pkb(s0[14], s0[15]);
        plswap(c0, d0); plswap(c1, d1);
        u4 w1; w1[0] = c0; w1[1] = c1; w1[2] = d0; w1[3] = d1;
        pa[1] = __builtin_bit_cast(s8, w1);
    }

    // Y += P V  (V prefetched into regs one tile ago; no wait needed)
    __builtin_amdgcn_s_setprio(1);
#pragma unroll
    for (int ks = 0; ks < 2; ks++) {
        y0 = MFMA32B(pa[ks], vf[ks][0], y0);
        y1 = MFMA32B(pa[ks], vf[ks][1], y1);
    }
    __builtin_amdgcn_s_setprio(0);
}

__global__ __launch_bounds__(64) void attn_kernel(const f16* __restrict__ Q,
                                                  const f16* __restrict__ K,
                                                  const unsigned short* __restrict__ Vg,
                                                  f16* __restrict__ O) {
    __shared__ f16 lK[2][2048];  // [buf][32 rows x 64]
    const int lane = threadIdx.x;
    const int hi = lane >> 5, ln = lane & 31;
    const int bh = blockIdx.x & 63;
    const int p = (int)(blockIdx.x >> 6);  // 0..31
    const f16* Qb = Q + (size_t)bh * 2048 * 64;
    const f16* Kb = K + (size_t)bh * 2048 * 64;
    const unsigned short* Vb = Vg + (size_t)bh * 64 * 2048;
    const int b = bh >> 4, hh = bh & 15;

    for (int ph = 0; ph < 2; ph++) {
        const int qt = ph ? p : 63 - p;  // complementary pair: total 65 tiles/block, uniform
        const int qw = qt * 32;

        // hoist Q fragments (B-operand): Q[qw+ln][dd*16 + hi*8 .. +8]
        h8 qf[4];
#pragma unroll
        for (int dd = 0; dd < 4; dd++)
            qf[dd] = *(const h8*)(Qb + (size_t)(qw + ln) * 64 + dd * 16 + hi * 8);

        float lpart = 0.f;
        f16x y0, y1;
#pragma unroll
        for (int r = 0; r < 16; r++) { y0[r] = 0.f; y1[r] = 0.f; }

        const int nt = qt + 1;  // tiles of 32; last tile k0 == qw

        // prologue: stage K(0) -> lK[0], V(0) -> vfA
        s8 vfA[2][2], vfB[2][2];
#pragma unroll
        for (int i = 0; i < 4; i++) {
            int s = i * 64 + lane;
            int row = s >> 3;
            int gc = ((s & 7) ^ (row & 7)) * 8;
            gload16(Kb + (size_t)row * 64 + gc, &lK[0][i * 512]);
        }
#pragma unroll
        for (int ks = 0; ks < 2; ks++)
#pragma unroll
            for (int j = 0; j < 2; j++)
                vfA[ks][j] = *(const s8*)(Vb + (size_t)(j * 32 + ln) * 2048 + ks * 16 + hi * 8);

        for (int it = 0; it < nt; it += 2) {
            attn_tile(it * 32, it == nt - 1, it + 1 < nt, lane, hi, ln, Kb, Vb,
                      &lK[0][0], &lK[1][0], qf, vfA, vfB, lpart, y0, y1);
            if (it + 1 < nt)
                attn_tile((it + 1) * 32, it + 1 == nt - 1, it + 2 < nt, lane, hi, ln, Kb, Vb,
                          &lK[1][0], &lK[0][0], qf, vfB, vfA, lpart, y0, y1);
        }

        // phase epilogue: combine half-lane partials, normalize, store
        float lT = lpart + __shfl_xor(lpart, 32);
        float inv = 1.0f / lT;
#pragma unroll
        for (int r = 0; r < 16; r++) {
            int crow = (r & 3) + 8 * (r >> 2) + 4 * hi;
            float invr = __shfl(inv, crow);
            size_t base = ((size_t)(b * 2048 + qw + crow)) * 1024 + hh * 64 + ln;
            O[base] = (f16)(y0[r] * invr);
            O[base + 32] = (f16)(y1[r] * invr);
        }
    }
}

// ---------------- launch ----------------

extern "C" void kernel_launch(void* const* d_in, const int* in_sizes, int n_in,
                              void* d_out, int out_size, void* d_ws, size_t ws_size,
                              hipStream_t stream) {
    const float* x      = (const float*)d_in[0];
    const float* W_attn = (const float*)d_in[1];
    const float* b_attn = (const float*)d_in[2];
    const float* W_proj = (const float*)d_in[3];
    const float* b_proj = (const float*)d_in[4];
    float* out = (float*)d_out;

    char* ws = (char*)d_ws;
    f16* xb  = (f16*)ws;                                   // 16 MB (reused as attn out)
    f16* Wat = (f16*)(ws + 16777216);                      // 6 MB
    f16* Wpt = (f16*)(ws + 16777216 + 6291456);            // 2 MB
    unsigned short* Vt = (unsigned short*)(ws + 16777216 + 6291456 + 2097152);  // 16 MB (bf16)
    f16* Qs  = (f16*)d_out;                                // scratch: first 16 MB of out
    f16* Ks  = (f16*)((char*)d_out + 16777216);            // scratch: second 16 MB of out

    cvt_f16_kernel<<<4096, 256, 0, stream>>>(x, xb, 1048576);
    transpose_cvt<<<dim3(96, 32), dim3(32, 8), 0, stream>>>(W_attn, Wat, 1024, 3072);
    transpose_cvt<<<dim3(32, 32), dim3(32, 8), 0, stream>>>(W_proj, Wpt, 1024, 1024);
    qkv_gemm<<<1536, 256, 0, stream>>>(xb, Wat, b_attn, Qs, Ks, Vt);
    attn_kernel<<<2048, 64, 0, stream>>>(Qs, Ks, Vt, xb);
    proj_gemm<<<512, 256, 0, stream>>>(xb, Wpt, b_proj, out);
}